// Round 16
// baseline (166.017 us; speedup 1.0000x reference)
//
#include <hip/hip_runtime.h>

#define D 512
#define H 8
#define HD 64
#define NQ 2048
#define NC 4096
#define SPLIT 8
#define CLEN (NC / SPLIT)   // 512 contexts per split chunk
#define NT (CLEN / 32)      // 16 tiles per chunk
#define M0 3.0f             // fixed softmax max: scores provably < 3
#define KP 72               // K LDS row stride (shorts): 144B, 16B-aligned
#define VP 40               // V LDS row stride (shorts): 80B, 16B-aligned

// tiled-GEMM geometry (TBM=64, round-15 PASSED)
#define TBM 64
#define TBN 64
#define TBK 32
#define TPAD 40             // LDS row stride in shorts: 80B, 16B-aligned

typedef __attribute__((ext_vector_type(8))) short short8;
typedef __attribute__((ext_vector_type(4))) short short4v;
typedef __attribute__((ext_vector_type(4))) float float4v;
typedef __attribute__((ext_vector_type(4))) int int4v;

__device__ inline float bf2f(short s) {
    unsigned int u = ((unsigned int)(unsigned short)s) << 16;
    return __builtin_bit_cast(float, u);
}
__device__ inline short f2bf(float f) {
    unsigned int u = __builtin_bit_cast(unsigned int, f);
    u = (u + 0x7FFF + ((u >> 16) & 1)) >> 16;   // round-to-nearest-even
    return (short)u;
}
// pack two f32 -> one dword of 2 bf16 (RNE), single HW instruction
__device__ inline int cvtpk(float a, float b) {
    int w;
    asm("v_cvt_pk_bf16_f32 %0, %1, %2" : "=v"(w) : "v"(a), "v"(b));
    return w;
}

// ---------------------------------------------------------------------------
// Cast f32 -> bf16 for the 6 MFMA-operand tensors. Grid 4096 x 256.
// ---------------------------------------------------------------------------
__global__ __launch_bounds__(256) void cast_all(
    const float* __restrict__ s0, const float* __restrict__ s1,
    const float* __restrict__ s2, const float* __restrict__ s3,
    const float* __restrict__ s4, const float* __restrict__ s5,
    short* __restrict__ dst)
{
    int i = blockIdx.x * 256 + threadIdx.x;
    const float* src; int off;
    if      (i < 262144) { src = s0; off = i; }
    else if (i < 786432) { src = s1; off = i - 262144; }
    else if (i < 851968) { src = s2; off = i - 786432; }
    else if (i < 917504) { src = s3; off = i - 851968; }
    else if (i < 983040) { src = s4; off = i - 917504; }
    else                 { src = s5; off = i - 983040; }
    float4v v = ((const float4v*)src)[off];
    short4v o;
    o.x = f2bf(v.x); o.y = f2bf(v.y); o.z = f2bf(v.z); o.w = f2bf(v.w);
    ((short4v*)dst)[i] = o;
}

// ---------------------------------------------------------------------------
// GEMM: out[M x D] = X @ W^T + bias. Wave computes 16x64 (fallback path).
// ---------------------------------------------------------------------------
__global__ __launch_bounds__(256) void gemm_bt_bias(
    const short* __restrict__ X, const short* __restrict__ W,
    const float* __restrict__ bias, short* __restrict__ out, int M)
{
    int wave = threadIdx.x >> 6, lane = threadIdx.x & 63;
    int gt = blockIdx.x * 4 + wave;
    int tm = gt >> 3;
    int tg = gt & 7;
    if (tm >= (M >> 4)) return;
    int l15 = lane & 15, quad = lane >> 4;
    const short* xp = X + (tm * 16 + l15) * D + quad * 8;
    const short* wp = W + (tg * 64 + l15) * D + quad * 8;
    float4v a0 = {0,0,0,0}, a1 = {0,0,0,0}, a2 = {0,0,0,0}, a3 = {0,0,0,0};
#pragma unroll
    for (int k = 0; k < D; k += 32) {
        short8 a  = *(const short8*)(xp + k);
        short8 b0 = *(const short8*)(wp + k);
        short8 b1 = *(const short8*)(wp + 16 * D + k);
        short8 b2 = *(const short8*)(wp + 32 * D + k);
        short8 b3 = *(const short8*)(wp + 48 * D + k);
        a0 = __builtin_amdgcn_mfma_f32_16x16x32_bf16(a, b0, a0, 0, 0, 0);
        a1 = __builtin_amdgcn_mfma_f32_16x16x32_bf16(a, b1, a1, 0, 0, 0);
        a2 = __builtin_amdgcn_mfma_f32_16x16x32_bf16(a, b2, a2, 0, 0, 0);
        a3 = __builtin_amdgcn_mfma_f32_16x16x32_bf16(a, b3, a3, 0, 0, 0);
    }
    int orow = tm * 16 + quad * 4;
    float4v accs[4] = {a0, a1, a2, a3};
#pragma unroll
    for (int j = 0; j < 4; j++) {
        int col = tg * 64 + j * 16 + l15;
        float bv = bias[col];
#pragma unroll
        for (int r = 0; r < 4; r++)
            out[(orow + r) * D + col] = f2bf(accs[j][r] + bv);
    }
}

// ---------------------------------------------------------------------------
// TILED Q+K+V projection GEMM, TBM=64 (round-15 PASSED). XCD remap kept.
// Grid 1280: 0..255 Q (MT=32) | 256..767 K (MT=64) | 768..1279 V (MT=64).
// ---------------------------------------------------------------------------
__global__ __launch_bounds__(256) void gemm_qkv_tiled(
    const short* __restrict__ Xq, const short* __restrict__ Xc,
    const short* __restrict__ Wq, const short* __restrict__ Wk,
    const short* __restrict__ Wv,
    const float* __restrict__ bq, const float* __restrict__ bk,
    const float* __restrict__ bv,
    short* __restrict__ Qout, short* __restrict__ Kout,
    short* __restrict__ VoutT)
{
    __shared__ __align__(16) short Ab[2][TBM * TPAD];   // 10240 B
    __shared__ __align__(16) short Bb[2][TBN * TPAD];   // 10240 B

    int tid = threadIdx.x;
    int wave = tid >> 6, lane = tid & 63;
    int quad = lane >> 4, l15 = lane & 15;

    int blk = blockIdx.x;
    const short *X, *W;
    const float* bias;
    short* outp;
    int bm, bn, vmode;
    {
        int local, mtdiv8;
        if (blk < 256)      { local = blk;       mtdiv8 = 4; }   // Q: MT=32
        else if (blk < 768) { local = blk - 256; mtdiv8 = 8; }   // K: MT=64
        else                { local = blk - 768; mtdiv8 = 8; }   // V: MT=64
        int x = local & 7, y = local >> 3;
        int m = x * mtdiv8 + (y >> 3);
        int n = y & 7;
        bm = m * TBM; bn = n * TBN;
    }
    if (blk < 256)      { X = Xq; W = Wq; bias = bq; outp = Qout;  vmode = 0; }
    else if (blk < 768) { X = Xc; W = Wk; bias = bk; outp = Kout;  vmode = 0; }
    else                { X = Xc; W = Wv; bias = bv; outp = VoutT; vmode = 1; }

    int ar = tid >> 2, ac = (tid & 3) * 8;
    int br = tid >> 2, bc = (tid & 3) * 8;
    const short* ag = X + (size_t)(bm + ar) * D + ac;
    const short* bg = W + (size_t)(bn + br) * D + bc;
    short* aw0 = &Ab[0][ar * TPAD + ac];
    short* aw1 = &Ab[1][ar * TPAD + ac];
    short* bw0 = &Bb[0][br * TPAD + bc];
    short* bw1 = &Bb[1][br * TPAD + bc];

    short8 ra, rb;

#define GLOAD(ks) {                                                            \
        ra = *(const short8*)(ag + (ks) * TBK);                                \
        rb = *(const short8*)(bg + (ks) * TBK); }
#define GDSW0 { *(short8*)aw0 = ra; *(short8*)bw0 = rb; }
#define GDSW1 { *(short8*)aw1 = ra; *(short8*)bw1 = rb; }

    float4v c00 = {0,0,0,0}, c01 = {0,0,0,0}, c02 = {0,0,0,0}, c03 = {0,0,0,0};

#define GCOMP(B)                                                               \
    {                                                                          \
        const short* abase = &Ab[B][(wave * 16 + l15) * TPAD + quad * 8];      \
        const short* bbase = &Bb[B][l15 * TPAD + quad * 8];                    \
        short8 a0 = *(const short8*)(abase);                                   \
        short8 b0 = *(const short8*)(bbase);                                   \
        short8 b1 = *(const short8*)(bbase + 16 * TPAD);                       \
        short8 b2 = *(const short8*)(bbase + 32 * TPAD);                       \
        short8 b3 = *(const short8*)(bbase + 48 * TPAD);                       \
        c00 = __builtin_amdgcn_mfma_f32_16x16x32_bf16(a0, b0, c00, 0, 0, 0);   \
        c01 = __builtin_amdgcn_mfma_f32_16x16x32_bf16(a0, b1, c01, 0, 0, 0);   \
        c02 = __builtin_amdgcn_mfma_f32_16x16x32_bf16(a0, b2, c02, 0, 0, 0);   \
        c03 = __builtin_amdgcn_mfma_f32_16x16x32_bf16(a0, b3, c03, 0, 0, 0);   \
    }

    GLOAD(0);
    GDSW0;
    GLOAD(1);
    __syncthreads();

    for (int t = 0; t < 14; t += 2) {
        GDSW1;
        GLOAD(t + 2);
        GCOMP(0);
        __syncthreads();
        GDSW0;
        GLOAD(t + 3);
        GCOMP(1);
        __syncthreads();
    }
    GDSW1;
    GCOMP(0);
    __syncthreads();
    GCOMP(1);

#undef GLOAD
#undef GDSW0
#undef GDSW1
#undef GCOMP

    float4v accs[4] = {c00, c01, c02, c03};
    if (vmode == 0) {
        int orow = bm + wave * 16 + quad * 4;
#pragma unroll
        for (int nf = 0; nf < 4; nf++) {
            int col = bn + nf * 16 + l15;
            float bb_ = bias[col];
#pragma unroll
            for (int r = 0; r < 4; r++)
                outp[(size_t)(orow + r) * D + col] = f2bf(accs[nf][r] + bb_);
        }
    } else {
        int orow = bm + wave * 16 + quad * 4;   // 4-aligned context base
        int a = (orow & 31) >> 2;
        int posb = (a < 4) ? (8 * a) : (8 * (a - 4) + 4);
        int cp = (orow & ~31) + posb;
#pragma unroll
        for (int nf = 0; nf < 4; nf++) {
            int col = bn + nf * 16 + l15;
            float bb_ = bias[col];
            short4v o;
#pragma unroll
            for (int r = 0; r < 4; r++) o[r] = f2bf(accs[nf][r] + bb_);
            *(short4v*)(outp + (size_t)col * NC + cp) = o;
        }
    }
}

// ---------------------------------------------------------------------------
// TILED output projection: Xf = Att @ Wo^T + bo + resid (f32 out).
// TBM=64 (round-15 PASSED) + XCD remap (MT=32). Grid 256.
// ---------------------------------------------------------------------------
__global__ __launch_bounds__(256) void gemm_out_tiled(
    const short* __restrict__ X, const short* __restrict__ W,
    const float* __restrict__ bias, const float* __restrict__ resid,
    float* __restrict__ out)
{
    __shared__ __align__(16) short Ab[2][TBM * TPAD];   // 10240 B
    __shared__ __align__(16) short Bb[2][TBN * TPAD];   // 10240 B

    int tid = threadIdx.x;
    int wave = tid >> 6, lane = tid & 63;
    int quad = lane >> 4, l15 = lane & 15;

    int blk = blockIdx.x;
    int x = blk & 7, y = blk >> 3;          // y in [0,32)
    int bm = (x * 4 + (y >> 3)) * TBM;      // MT=32
    int bn = (y & 7) * TBN;

    int ar = tid >> 2, ac = (tid & 3) * 8;
    int br = tid >> 2, bc = (tid & 3) * 8;
    const short* ag = X + (size_t)(bm + ar) * D + ac;
    const short* bg = W + (size_t)(bn + br) * D + bc;
    short* aw0 = &Ab[0][ar * TPAD + ac];
    short* aw1 = &Ab[1][ar * TPAD + ac];
    short* bw0 = &Bb[0][br * TPAD + bc];
    short* bw1 = &Bb[1][br * TPAD + bc];

    short8 ra, rb;

#define GLOAD(ks) {                                                            \
        ra = *(const short8*)(ag + (ks) * TBK);                                \
        rb = *(const short8*)(bg + (ks) * TBK); }
#define GDSW0 { *(short8*)aw0 = ra; *(short8*)bw0 = rb; }
#define GDSW1 { *(short8*)aw1 = ra; *(short8*)bw1 = rb; }

    float4v c00 = {0,0,0,0}, c01 = {0,0,0,0}, c02 = {0,0,0,0}, c03 = {0,0,0,0};

#define GCOMP(B)                                                               \
    {                                                                          \
        const short* abase = &Ab[B][(wave * 16 + l15) * TPAD + quad * 8];      \
        const short* bbase = &Bb[B][l15 * TPAD + quad * 8];                    \
        short8 a0 = *(const short8*)(abase);                                   \
        short8 b0 = *(const short8*)(bbase);                                   \
        short8 b1 = *(const short8*)(bbase + 16 * TPAD);                       \
        short8 b2 = *(const short8*)(bbase + 32 * TPAD);                       \
        short8 b3 = *(const short8*)(bbase + 48 * TPAD);                       \
        c00 = __builtin_amdgcn_mfma_f32_16x16x32_bf16(a0, b0, c00, 0, 0, 0);   \
        c01 = __builtin_amdgcn_mfma_f32_16x16x32_bf16(a0, b1, c01, 0, 0, 0);   \
        c02 = __builtin_amdgcn_mfma_f32_16x16x32_bf16(a0, b2, c02, 0, 0, 0);   \
        c03 = __builtin_amdgcn_mfma_f32_16x16x32_bf16(a0, b3, c03, 0, 0, 0);   \
    }

    GLOAD(0);
    GDSW0;
    GLOAD(1);
    __syncthreads();

    for (int t = 0; t < 14; t += 2) {
        GDSW1;
        GLOAD(t + 2);
        GCOMP(0);
        __syncthreads();
        GDSW0;
        GLOAD(t + 3);
        GCOMP(1);
        __syncthreads();
    }
    GDSW1;
    GCOMP(0);
    __syncthreads();
    GCOMP(1);

#undef GLOAD
#undef GDSW0
#undef GDSW1
#undef GCOMP

    float4v accs[4] = {c00, c01, c02, c03};
    int orow = bm + wave * 16 + quad * 4;
#pragma unroll
    for (int nf = 0; nf < 4; nf++) {
        int col = bn + nf * 16 + l15;
        float bb_ = bias[col];
#pragma unroll
        for (int r = 0; r < 4; r++)
            out[(size_t)(orow + r) * D + col] =
                accs[nf][r] + bb_ + resid[(size_t)(orow + r) * D + col];
    }
}

// Fallback: naive res GEMM writing f32 (used with separate layernorm_kernel).
__global__ __launch_bounds__(256) void gemm_bt_bias_res_f32(
    const short* __restrict__ X, const short* __restrict__ W,
    const float* __restrict__ bias, const float* __restrict__ resid,
    float* __restrict__ out, int M)
{
    int wave = threadIdx.x >> 6, lane = threadIdx.x & 63;
    int gt = blockIdx.x * 4 + wave;
    int tm = gt >> 3;
    int tg = gt & 7;
    if (tm >= (M >> 4)) return;
    int l15 = lane & 15, quad = lane >> 4;
    const short* xp = X + (tm * 16 + l15) * D + quad * 8;
    const short* wp = W + (tg * 64 + l15) * D + quad * 8;
    float4v a0 = {0,0,0,0}, a1 = {0,0,0,0}, a2 = {0,0,0,0}, a3 = {0,0,0,0};
#pragma unroll
    for (int k = 0; k < D; k += 32) {
        short8 a  = *(const short8*)(xp + k);
        short8 b0 = *(const short8*)(wp + k);
        short8 b1 = *(const short8*)(wp + 16 * D + k);
        short8 b2 = *(const short8*)(wp + 32 * D + k);
        short8 b3 = *(const short8*)(wp + 48 * D + k);
        a0 = __builtin_amdgcn_mfma_f32_16x16x32_bf16(a, b0, a0, 0, 0, 0);
        a1 = __builtin_amdgcn_mfma_f32_16x16x32_bf16(a, b1, a1, 0, 0, 0);
        a2 = __builtin_amdgcn_mfma_f32_16x16x32_bf16(a, b2, a2, 0, 0, 0);
        a3 = __builtin_amdgcn_mfma_f32_16x16x32_bf16(a, b3, a3, 0, 0, 0);
    }
    int orow = tm * 16 + quad * 4;
    float4v accs[4] = {a0, a1, a2, a3};
#pragma unroll
    for (int j = 0; j < 4; j++) {
        int col = tg * 64 + j * 16 + l15;
        float bv = bias[col];
#pragma unroll
        for (int r = 0; r < 4; r++) {
            int q = orow + r;
            out[q * D + col] = accs[j][r] + bv + resid[q * D + col];
        }
    }
}

// ---------------------------------------------------------------------------
// MFMA flash attention v11: UN-PAIRED heads (v5 skeleton: 1 head/block) with
// all verified v9/v10 numerics (exp2+escale+M0L, cvtpk, builtin sqrt, halved
// ccl+refill, XCD swizzle). Rationale: per-score VALU is now ~3x cheaper
// than at v6, so trading +33% dist-VALU for occupancy 22% -> ~40% (LDS
// 39936 -> 21504 B = 7 blocks/CU; grid 2048 = 8/CU) wins on a kernel where
// both pipes sit at ~50% busy (latency-limited).
// Swizzle: s=(d&7)*256+(d>>3); bx=s&31, by=(s>>5)&7, bz=s>>8 (bijective;
// d&7==bz so all 32 q-blocks of a (head,chunk) share one XCD; K/V slab
// 128KB per L2). Numerics identical to v10 (same formulas, same inputs).
// NOTE: cc-from-global (v7/v8) produced NaN twice — do not reintroduce.
// Block = (64 q, 1 head, 1 chunk). Grid 2048.
// ---------------------------------------------------------------------------
__global__ __launch_bounds__(256) void attn_mfma_split11(
    const short* __restrict__ Q, const short* __restrict__ K,
    const short* __restrict__ Vp,
    const float* __restrict__ qc, const float* __restrict__ cc,
    const float* __restrict__ log_scale, const float* __restrict__ bph,
    short* __restrict__ Opart, float* __restrict__ Lpart)
{
    __shared__ __align__(16) short Klds[2][32 * KP];    //  9216 B
    __shared__ __align__(16) short Vlds[2][64 * VP];    // 10240 B
    __shared__ __align__(16) float ccl[512];            //  2048 B (256 ctx)

    int tid = threadIdx.x;
    int wave = tid >> 6, lane = tid & 63;

    // XCD swizzle decode (grid 2048)
    int d = blockIdx.x;
    int s = (d & 7) * 256 + (d >> 3);
    int bx = s & 31;
    int by = (s >> 5) & 7;
    int bz = s >> 8;

    int h = by;
    int sp = bz;
    int q0 = bx * 64 + wave * 16;
    int quad = lane >> 4, l15 = lane & 15;
    int cbase = sp * CLEN;

    const float LOG2E = 1.4426950408889634f;
    const float escale = 0.125f * LOG2E;
    const float M0L = M0 * LOG2E;
    float bh = __expf(log_scale[0]) * bph[h] * LOG2E;

    const short* qp = Q + (q0 + l15) * D + h * HD + quad * 8;
    short8 qa0 = *(const short8*)(qp);
    short8 qa1 = *(const short8*)(qp + 32);

    float qx = qc[(q0 + l15) * 2];
    float qy = qc[(q0 + l15) * 2 + 1];

    float lacc = 0.f;
    float4v O0 = {0,0,0,0}, O1 = {0,0,0,0}, O2 = {0,0,0,0}, O3 = {0,0,0,0};

    // staging maps (v5-verified): K 32 rows x 64 shorts (r=tid>>3, c=tid&7);
    // V 64 rows x 32 shorts (r=tid>>2, c=tid&3). 1 short8/thread each.
    int kr_ = tid >> 3, kc_ = tid & 7;
    int vr_ = tid >> 2, vc_ = tid & 3;
    const short* kg = K + (size_t)h * HD + kc_ * 8;              // +(c0+kr_)*D
    const short* vg = Vp + (size_t)(h * HD + vr_) * NC + vc_ * 8;        // +c0
    short* kw0 = &Klds[0][kr_ * KP + kc_ * 8];
    short* kw1 = &Klds[1][kr_ * KP + kc_ * 8];
    short* vw0 = &Vlds[0][vr_ * VP + vc_ * 8];
    short* vw1 = &Vlds[1][vr_ * VP + vc_ * 8];

    short8 rk, rv;   // staged regs for the next tile

#define LOADR(c0_)                                                             \
    rk = *(const short8*)(kg + (size_t)((c0_) + kr_) * D);                     \
    rv = *(const short8*)(vg + (c0_));

#define DSW0  { *(short8*)kw0 = rk; *(short8*)vw0 = rv; }
#define DSW1  { *(short8*)kw1 = rk; *(short8*)vw1 = rv; }

    const float2* ccp = (const float2*)ccl;

    // lo = context offset RELATIVE to the current ccl phase (0..224)
#define COMPUTE_TILE(B, lo)                                                    \
    {                                                                          \
        const short* kb = &Klds[B][0];                                         \
        const short* vb = &Vlds[B][0];                                         \
        short8 k00 = *(const short8*)(kb + l15 * KP + quad * 8);               \
        short8 k01 = *(const short8*)(kb + l15 * KP + 32 + quad * 8);          \
        short8 k10 = *(const short8*)(kb + (16 + l15) * KP + quad * 8);        \
        short8 k11 = *(const short8*)(kb + (16 + l15) * KP + 32 + quad * 8);   \
        float4v s0 = {0,0,0,0}, s1 = {0,0,0,0};                                \
        s0 = __builtin_amdgcn_mfma_f32_16x16x32_bf16(k00, qa0, s0, 0, 0, 0);   \
        s0 = __builtin_amdgcn_mfma_f32_16x16x32_bf16(k01, qa1, s0, 0, 0, 0);   \
        s1 = __builtin_amdgcn_mfma_f32_16x16x32_bf16(k10, qa0, s1, 0, 0, 0);   \
        s1 = __builtin_amdgcn_mfma_f32_16x16x32_bf16(k11, qa1, s1, 0, 0, 0);   \
        short8 v0 = *(const short8*)(vb + l15 * VP + quad * 8);                \
        short8 v1 = *(const short8*)(vb + (16 + l15) * VP + quad * 8);         \
        short8 v2 = *(const short8*)(vb + (32 + l15) * VP + quad * 8);         \
        short8 v3 = *(const short8*)(vb + (48 + l15) * VP + quad * 8);         \
        float2 ca0 = ccp[(lo) + 4 * quad + 0], cb0 = ccp[(lo) + 16 + 4 * quad + 0];\
        float2 ca1 = ccp[(lo) + 4 * quad + 1], cb1 = ccp[(lo) + 16 + 4 * quad + 1];\
        float2 ca2 = ccp[(lo) + 4 * quad + 2], cb2 = ccp[(lo) + 16 + 4 * quad + 2];\
        float2 ca3 = ccp[(lo) + 4 * quad + 3], cb3 = ccp[(lo) + 16 + 4 * quad + 3];\
        float dx, dy;                                                          \
        dx = qx - ca0.x; dy = qy - ca0.y;                                      \
        float dA0 = __builtin_amdgcn_sqrtf(__fmaf_rn(dx, dx, dy * dy));        \
        dx = qx - ca1.x; dy = qy - ca1.y;                                      \
        float dA1 = __builtin_amdgcn_sqrtf(__fmaf_rn(dx, dx, dy * dy));        \
        dx = qx - ca2.x; dy = qy - ca2.y;                                      \
        float dA2 = __builtin_amdgcn_sqrtf(__fmaf_rn(dx, dx, dy * dy));        \
        dx = qx - ca3.x; dy = qy - ca3.y;                                      \
        float dA3 = __builtin_amdgcn_sqrtf(__fmaf_rn(dx, dx, dy * dy));        \
        dx = qx - cb0.x; dy = qy - cb0.y;                                      \
        float dB0 = __builtin_amdgcn_sqrtf(__fmaf_rn(dx, dx, dy * dy));        \
        dx = qx - cb1.x; dy = qy - cb1.y;                                      \
        float dB1 = __builtin_amdgcn_sqrtf(__fmaf_rn(dx, dx, dy * dy));        \
        dx = qx - cb2.x; dy = qy - cb2.y;                                      \
        float dB2 = __builtin_amdgcn_sqrtf(__fmaf_rn(dx, dx, dy * dy));        \
        dx = qx - cb3.x; dy = qy - cb3.y;                                      \
        float dB3 = __builtin_amdgcn_sqrtf(__fmaf_rn(dx, dx, dy * dy));        \
        float p00 = exp2f(__fmaf_rn(s0[0], escale, __fmaf_rn(-bh, dA0, -M0L)));\
        float p01 = exp2f(__fmaf_rn(s0[1], escale, __fmaf_rn(-bh, dA1, -M0L)));\
        float p02 = exp2f(__fmaf_rn(s0[2], escale, __fmaf_rn(-bh, dA2, -M0L)));\
        float p03 = exp2f(__fmaf_rn(s0[3], escale, __fmaf_rn(-bh, dA3, -M0L)));\
        float p10 = exp2f(__fmaf_rn(s1[0], escale, __fmaf_rn(-bh, dB0, -M0L)));\
        float p11 = exp2f(__fmaf_rn(s1[1], escale, __fmaf_rn(-bh, dB1, -M0L)));\
        float p12 = exp2f(__fmaf_rn(s1[2], escale, __fmaf_rn(-bh, dB2, -M0L)));\
        float p13 = exp2f(__fmaf_rn(s1[3], escale, __fmaf_rn(-bh, dB3, -M0L)));\
        lacc += ((p00 + p01) + (p02 + p03)) + ((p10 + p11) + (p12 + p13));     \
        int4v pw;                                                              \
        pw.x = cvtpk(p00, p01); pw.y = cvtpk(p02, p03);                        \
        pw.z = cvtpk(p10, p11); pw.w = cvtpk(p12, p13);                        \
        short8 pa = __builtin_bit_cast(short8, pw);                            \
        O0 = __builtin_amdgcn_mfma_f32_16x16x32_bf16(pa, v0, O0, 0, 0, 0);     \
        O1 = __builtin_amdgcn_mfma_f32_16x16x32_bf16(pa, v1, O1, 0, 0, 0);     \
        O2 = __builtin_amdgcn_mfma_f32_16x16x32_bf16(pa, v2, O2, 0, 0, 0);     \
        O3 = __builtin_amdgcn_mfma_f32_16x16x32_bf16(pa, v3, O3, 0, 0, 0);     \
    }

    // ---- prologue: cc phase A (256 ctx) -> LDS, tile0 -> buf0, tile1 -> regs
    ((float2*)ccl)[tid] = ((const float2*)cc)[cbase + tid];
    LOADR(cbase);
    DSW0;
    LOADR(cbase + 32);
    __syncthreads();

    // ---- main loop: 16 tiles, 2x-unrolled; ccl refill at t==8 ----
    for (int t = 0; t < NT - 2; t += 2) {
        int c0 = cbase + t * 32;
        if (t == 8) {
            ((float2*)ccl)[tid] = ((const float2*)cc)[cbase + 256 + tid];
            __syncthreads();
        }
        DSW1;
        LOADR(c0 + 64);
        COMPUTE_TILE(0, (t & 7) * 32);
        __syncthreads();
        DSW0;
        LOADR(c0 + 96);
        COMPUTE_TILE(1, (t & 7) * 32 + 32);
        __syncthreads();
    }
    DSW1;
    COMPUTE_TILE(0, 192);   // tile 14, rel (14-8)*32
    __syncthreads();
    COMPUTE_TILE(1, 224);   // tile 15, rel (15-8)*32

#undef LOADR
#undef DSW0
#undef DSW1
#undef COMPUTE_TILE

    // L reduction: sum per q=l15 across the 4 quads (lanes +-16, +-32)
    lacc += __shfl_xor(lacc, 16);
    lacc += __shfl_xor(lacc, 32);

    long base = (long)(sp * H + h) * NQ;
    float4v Oarr[4] = {O0, O1, O2, O3};
#pragma unroll
    for (int t = 0; t < 4; t++) {
#pragma unroll
        for (int r = 0; r < 4; r++) {
            int q = q0 + quad * 4 + r;
            Opart[(base + q) * HD + t * 16 + l15] = f2bf(Oarr[t][r]);
        }
    }
    if (lane < 16)
        Lpart[base + q0 + lane] = lacc;
}

// Plain-sum combine (all splits share fixed max M0) -> bf16 Att.
__global__ __launch_bounds__(256) void attn_combine(
    const short* __restrict__ Opart, const float* __restrict__ Lpart,
    short* __restrict__ Att)
{
    int id = blockIdx.x * 256 + threadIdx.x;   // over H*NQ*HD = 2^20
    int d = id & 63;
    int q = (id >> 6) & (NQ - 1);
    int h = id >> 17;
    float L = 0.f, acc = 0.f;
#pragma unroll
    for (int s = 0; s < SPLIT; s++) {
        long b = (long)(s * H + h) * NQ + q;
        L   += Lpart[b];
        acc += bf2f(Opart[b * HD + d]);
    }
    Att[q * D + h * HD + d] = f2bf(acc / L);
}

// ---------------------------------------------------------------------------
// Fallback single-pass attention (exact online softmax) if ws is too small.
// Expects V row-major [NC][D], unscaled Q.
// ---------------------------------------------------------------------------
__global__ __launch_bounds__(256) void attn_mfma(
    const short* __restrict__ Q, const short* __restrict__ K,
    const short* __restrict__ V,
    const float* __restrict__ qc, const float* __restrict__ cc,
    const float* __restrict__ log_scale, const float* __restrict__ bph,
    short* __restrict__ out)
{
    __shared__ short Vt[HD][48];
    __shared__ short P[4][16][48];
    int wave = threadIdx.x >> 6, lane = threadIdx.x & 63;
    int h = blockIdx.y;
    int q0 = blockIdx.x * 64 + wave * 16;
    int quad = lane >> 4, l15 = lane & 15;
    const float scale = 0.125f;
    float bh = __expf(log_scale[0]) * bph[h];
    const short* qp = Q + (q0 + l15) * D + h * HD + quad * 8;
    short8 qa0 = *(const short8*)(qp);
    short8 qa1 = *(const short8*)(qp + 32);
    float qx[4], qy[4];
#pragma unroll
    for (int r = 0; r < 4; r++) {
        int q = q0 + quad * 4 + r;
        qx[r] = qc[q * 2]; qy[r] = qc[q * 2 + 1];
    }
    float m[4], l[4];
    float4v O[4];
#pragma unroll
    for (int r = 0; r < 4; r++) { m[r] = -1e30f; l[r] = 0.f; }
#pragma unroll
    for (int t = 0; t < 4; t++) O[t] = (float4v){0.f, 0.f, 0.f, 0.f};
    for (int c0 = 0; c0 < NC; c0 += 32) {
        __syncthreads();
        {
            int c = threadIdx.x >> 3;
            int dblk = (threadIdx.x & 7) * 8;
            short8 vv = *(const short8*)(V + (c0 + c) * D + h * HD + dblk);
#pragma unroll
            for (int j = 0; j < 8; j++) Vt[dblk + j][c] = vv[j];
        }
        const short* kp0 = K + (c0 + l15) * D + h * HD + quad * 8;
        const short* kp1 = kp0 + 16 * D;
        short8 kb00 = *(const short8*)(kp0);
        short8 kb01 = *(const short8*)(kp0 + 32);
        short8 kb10 = *(const short8*)(kp1);
        short8 kb11 = *(const short8*)(kp1 + 32);
        float4v s0 = {0,0,0,0}, s1 = {0,0,0,0};
        s0 = __builtin_amdgcn_mfma_f32_16x16x32_bf16(qa0, kb00, s0, 0, 0, 0);
        s0 = __builtin_amdgcn_mfma_f32_16x16x32_bf16(qa1, kb01, s0, 0, 0, 0);
        s1 = __builtin_amdgcn_mfma_f32_16x16x32_bf16(qa0, kb10, s1, 0, 0, 0);
        s1 = __builtin_amdgcn_mfma_f32_16x16x32_bf16(qa1, kb11, s1, 0, 0, 0);
        int cA = c0 + l15, cB = cA + 16;
        float cxA = cc[cA * 2], cyA = cc[cA * 2 + 1];
        float cxB = cc[cB * 2], cyB = cc[cB * 2 + 1];
#pragma unroll
        for (int r = 0; r < 4; r++) {
            float dxA = qx[r] - cxA, dyA = qy[r] - cyA;
            float dxB = qx[r] - cxB, dyB = qy[r] - cyB;
            float v0 = s0[r] * scale - bh * sqrtf(dxA * dxA + dyA * dyA);
            float v1 = s1[r] * scale - bh * sqrtf(dxB * dxB + dyB * dyB);
            float mx = fmaxf(v0, v1);
#pragma unroll
            for (int off = 1; off < 16; off <<= 1) mx = fmaxf(mx, __shfl_xor(mx, off));
            float mnew = fmaxf(m[r], mx);
            float alpha = __expf(m[r] - mnew);
            float p0 = __expf(v0 - mnew);
            float p1 = __expf(v1 - mnew);
            float ps = p0 + p1;
#pragma unroll
            for (int off = 1; off < 16; off <<= 1) ps += __shfl_xor(ps, off);
            l[r] = l[r] * alpha + ps;
            m[r] = mnew;
#pragma unroll
            for (int t = 0; t < 4; t++) O[t][r] *= alpha;
            P[wave][quad * 4 + r][l15]      = f2bf(p0);
            P[wave][quad * 4 + r][16 + l15] = f2bf(p1);
        }
        __syncthreads();
        short8 pa = *(const short8*)(&P[wave][l15][quad * 8]);
#pragma unroll
        for (int t = 0; t < 4; t++) {
            short8 vb = *(const short8*)(&Vt[t * 16 + l15][quad * 8]);
            O[t] = __builtin_amdgcn_mfma_f32_16x16x32_bf16(pa, vb, O[t], 0, 0, 0);
        }
    }
#pragma unroll
    for (int t = 0; t < 4; t++) {
#pragma unroll
        for (int r = 0; r < 4; r++) {
            int q = q0 + quad * 4 + r;
            out[q * D + h * HD + t * 16 + l15] = f2bf(O[t][r] / l[r]);
        }
    }
}

// ---------------------------------------------------------------------------
// Row LayerNorm: one wave per row of 512 f32, output f32. Grid NQ/4 = 512.
// ---------------------------------------------------------------------------
__global__ __launch_bounds__(256) void layernorm_kernel(
    const float* __restrict__ X, const float* __restrict__ g,
    const float* __restrict__ b, float* __restrict__ out)
{
    int wave = threadIdx.x >> 6, lane = threadIdx.x & 63;
    int row = blockIdx.x * 4 + wave;
    const float* xp = X + row * D;
    float v[8];
    float s = 0.f;
#pragma unroll
    for (int i = 0; i < 8; i++) { v[i] = xp[lane + i * 64]; s += v[i]; }
#pragma unroll
    for (int off = 1; off < 64; off <<= 1) s += __shfl_xor(s, off);
    float mu = s * (1.f / D);
    float var = 0.f;
#pragma unroll
    for (int i = 0; i < 8; i++) { float d = v[i] - mu; var += d * d; }
#pragma unroll
    for (int off = 1; off < 64; off <<= 1) var += __shfl_xor(var, off);
    float rstd = rsqrtf(var * (1.f / D) + 1e-5f);
#pragma unroll
    for (int i = 0; i < 8; i++) {
        int c = lane + i * 64;
        out[row * D + c] = (v[i] - mu) * rstd * g[c] + b[c];
    }
}

extern "C" void kernel_launch(void* const* d_in, const int* in_sizes, int n_in,
                              void* d_out, int out_size, void* d_ws, size_t ws_size,
                              hipStream_t stream) {
    const float* query_repr     = (const float*)d_in[0];
    const float* context_repr   = (const float*)d_in[1];
    const float* query_coords   = (const float*)d_in[2];
    const float* context_coords = (const float*)d_in[3];
    const float* Wq = (const float*)d_in[4];
    const float* bq = (const float*)d_in[5];
    const float* Wk = (const float*)d_in[6];
    const float* bk = (const float*)d_in[7];
    const float* Wv = (const float*)d_in[8];
    const float* bv = (const float*)d_in[9];
    const float* Wo = (const float*)d_in[10];
    const float* bo = (const float*)d_in[11];
    const float* ln_g = (const float*)d_in[12];
    const float* ln_b = (const float*)d_in[13];
    const float* log_scale = (const float*)d_in[14];
    const float* bph = (const float*)d_in[15];

    short* ws = (short*)d_ws;
    short* Xq_bf = ws;                       // 1,048,576 shorts
    short* Xc_bf = Xq_bf + NQ * D;           // 2,097,152
    short* Wq_bf = Xc_bf + NC * D;           //   262,144 x4
    short* Wk_bf = Wq_bf + D * D;
    short* Wv_bf = Wk_bf + D * D;
    short* Wo_bf = Wv_bf + D * D;
    short* Qw  = Wo_bf + D * D;              // 1,048,576
    short* Kw  = Qw + NQ * D;                // 2,097,152
    short* Vw  = Kw + NC * D;                // 2,097,152 (Vp [D][NC] permuted)
    short* Att = Vw + NC * D;                // 1,048,576
    float* Xf  = (float*)(Att + NQ * D);     // 1,048,576 f32
    short* Opart = (short*)(Xf + NQ * D);    // SPLIT*H*NQ*HD bf16 = 16.8 MB
    float* Lpart = (float*)(Opart + (size_t)SPLIT * H * NQ * HD);  // 0.5 MB
    size_t ws_needed_split = ((char*)(Lpart + (size_t)SPLIT * H * NQ)) - (char*)d_ws;

    // 1. cast MFMA operands to bf16
    cast_all<<<dim3(4096), 256, 0, stream>>>(
        query_repr, context_repr, Wq, Wk, Wv, Wo, Xq_bf);

    if (ws_size >= ws_needed_split) {
        // 2. TILED Q+K+V projection (TBM=64, grid 1280)
        gemm_qkv_tiled<<<dim3(1280), 256, 0, stream>>>(
            Xq_bf, Xc_bf, Wq_bf, Wk_bf, Wv_bf, bq, bk, bv, Qw, Kw, Vw);
        // 3. attention (v11: un-paired heads, 7 blocks/CU) + combine
        attn_mfma_split11<<<dim3(2048), 256, 0, stream>>>(
            Qw, Kw, Vw, query_coords, context_coords, log_scale, bph,
            Opart, Lpart);
        attn_combine<<<dim3(H * NQ * HD / 256), 256, 0, stream>>>(
            Opart, Lpart, Att);
        // 4. TILED output projection + residual (TBM=64, grid 256) -> Xf
        gemm_out_tiled<<<dim3(256), 256, 0, stream>>>(
            Att, Wo_bf, bo, query_repr, Xf);
        // 5. LayerNorm -> f32 output
        layernorm_kernel<<<dim3(NQ / 4), 256, 0, stream>>>(
            Xf, ln_g, ln_b, (float*)d_out);
    } else {
        gemm_bt_bias<<<dim3((NQ / 16) * 8 / 4), 256, 0, stream>>>(
            Xq_bf, Wq_bf, bq, Qw, NQ);
        gemm_bt_bias<<<dim3((NC / 16) * 8 / 4), 256, 0, stream>>>(
            Xc_bf, Wk_bf, bk, Kw, NC);
        gemm_bt_bias<<<dim3((NC / 16) * 8 / 4), 256, 0, stream>>>(
            Xc_bf, Wv_bf, bv, Vw, NC);
        attn_mfma<<<dim3(NQ / 64, H), 256, 0, stream>>>(
            Qw, Kw, Vw, query_coords, context_coords, log_scale, bph, Att);
        gemm_bt_bias_res_f32<<<dim3((NQ / 16) * 8 / 4), 256, 0, stream>>>(
            Att, Wo_bf, bo, query_repr, Xf, NQ);
        layernorm_kernel<<<dim3(NQ / 4), 256, 0, stream>>>(
            Xf, ln_g, ln_b, (float*)d_out);
    }
}

// Round 17
// 165.266 us; speedup vs baseline: 1.0045x; 1.0045x over previous
//
#include <hip/hip_runtime.h>

#define D 512
#define H 8
#define HD 64
#define NQ 2048
#define NC 4096
#define SPLIT 8
#define CLEN (NC / SPLIT)   // 512 contexts per split chunk
#define NT (CLEN / 32)      // 16 tiles per chunk
#define M0 3.0f             // fixed softmax max: scores provably < 3
#define KP2 136             // K LDS row stride (shorts): 272B, 16B-aligned
#define VP 40               // V LDS row stride (shorts): 80B, 16B-aligned

// tiled-GEMM geometry (TBM=64, round-15 PASSED at 164.5us)
#define TBM 64
#define TBN 64
#define TBK 32
#define TPAD 40             // LDS row stride in shorts: 80B, 16B-aligned

typedef __attribute__((ext_vector_type(8))) short short8;
typedef __attribute__((ext_vector_type(4))) short short4v;
typedef __attribute__((ext_vector_type(4))) float float4v;
typedef __attribute__((ext_vector_type(4))) int int4v;

__device__ inline float bf2f(short s) {
    unsigned int u = ((unsigned int)(unsigned short)s) << 16;
    return __builtin_bit_cast(float, u);
}
__device__ inline short f2bf(float f) {
    unsigned int u = __builtin_bit_cast(unsigned int, f);
    u = (u + 0x7FFF + ((u >> 16) & 1)) >> 16;   // round-to-nearest-even
    return (short)u;
}
// pack two f32 -> one dword of 2 bf16 (RNE), single HW instruction
__device__ inline int cvtpk(float a, float b) {
    int w;
    asm("v_cvt_pk_bf16_f32 %0, %1, %2" : "=v"(w) : "v"(a), "v"(b));
    return w;
}

// ---------------------------------------------------------------------------
// Cast f32 -> bf16 for the 6 MFMA-operand tensors. Grid 4096 x 256.
// ---------------------------------------------------------------------------
__global__ __launch_bounds__(256) void cast_all(
    const float* __restrict__ s0, const float* __restrict__ s1,
    const float* __restrict__ s2, const float* __restrict__ s3,
    const float* __restrict__ s4, const float* __restrict__ s5,
    short* __restrict__ dst)
{
    int i = blockIdx.x * 256 + threadIdx.x;
    const float* src; int off;
    if      (i < 262144) { src = s0; off = i; }
    else if (i < 786432) { src = s1; off = i - 262144; }
    else if (i < 851968) { src = s2; off = i - 786432; }
    else if (i < 917504) { src = s3; off = i - 851968; }
    else if (i < 983040) { src = s4; off = i - 917504; }
    else                 { src = s5; off = i - 983040; }
    float4v v = ((const float4v*)src)[off];
    short4v o;
    o.x = f2bf(v.x); o.y = f2bf(v.y); o.z = f2bf(v.z); o.w = f2bf(v.w);
    ((short4v*)dst)[i] = o;
}

// ---------------------------------------------------------------------------
// GEMM: out[M x D] = X @ W^T + bias. Wave computes 16x64 (fallback path).
// ---------------------------------------------------------------------------
__global__ __launch_bounds__(256) void gemm_bt_bias(
    const short* __restrict__ X, const short* __restrict__ W,
    const float* __restrict__ bias, short* __restrict__ out, int M)
{
    int wave = threadIdx.x >> 6, lane = threadIdx.x & 63;
    int gt = blockIdx.x * 4 + wave;
    int tm = gt >> 3;
    int tg = gt & 7;
    if (tm >= (M >> 4)) return;
    int l15 = lane & 15, quad = lane >> 4;
    const short* xp = X + (tm * 16 + l15) * D + quad * 8;
    const short* wp = W + (tg * 64 + l15) * D + quad * 8;
    float4v a0 = {0,0,0,0}, a1 = {0,0,0,0}, a2 = {0,0,0,0}, a3 = {0,0,0,0};
#pragma unroll
    for (int k = 0; k < D; k += 32) {
        short8 a  = *(const short8*)(xp + k);
        short8 b0 = *(const short8*)(wp + k);
        short8 b1 = *(const short8*)(wp + 16 * D + k);
        short8 b2 = *(const short8*)(wp + 32 * D + k);
        short8 b3 = *(const short8*)(wp + 48 * D + k);
        a0 = __builtin_amdgcn_mfma_f32_16x16x32_bf16(a, b0, a0, 0, 0, 0);
        a1 = __builtin_amdgcn_mfma_f32_16x16x32_bf16(a, b1, a1, 0, 0, 0);
        a2 = __builtin_amdgcn_mfma_f32_16x16x32_bf16(a, b2, a2, 0, 0, 0);
        a3 = __builtin_amdgcn_mfma_f32_16x16x32_bf16(a, b3, a3, 0, 0, 0);
    }
    int orow = tm * 16 + quad * 4;
    float4v accs[4] = {a0, a1, a2, a3};
#pragma unroll
    for (int j = 0; j < 4; j++) {
        int col = tg * 64 + j * 16 + l15;
        float bv = bias[col];
#pragma unroll
        for (int r = 0; r < 4; r++)
            out[(orow + r) * D + col] = f2bf(accs[j][r] + bv);
    }
}

// ---------------------------------------------------------------------------
// TILED Q+K+V projection GEMM, TBM=64 (round-15 PASSED). XCD remap kept.
// Grid 1280: 0..255 Q (MT=32) | 256..767 K (MT=64) | 768..1279 V (MT=64).
// ---------------------------------------------------------------------------
__global__ __launch_bounds__(256) void gemm_qkv_tiled(
    const short* __restrict__ Xq, const short* __restrict__ Xc,
    const short* __restrict__ Wq, const short* __restrict__ Wk,
    const short* __restrict__ Wv,
    const float* __restrict__ bq, const float* __restrict__ bk,
    const float* __restrict__ bv,
    short* __restrict__ Qout, short* __restrict__ Kout,
    short* __restrict__ VoutT)
{
    __shared__ __align__(16) short Ab[2][TBM * TPAD];   // 10240 B
    __shared__ __align__(16) short Bb[2][TBN * TPAD];   // 10240 B

    int tid = threadIdx.x;
    int wave = tid >> 6, lane = tid & 63;
    int quad = lane >> 4, l15 = lane & 15;

    int blk = blockIdx.x;
    const short *X, *W;
    const float* bias;
    short* outp;
    int bm, bn, vmode;
    {
        int local, mtdiv8;
        if (blk < 256)      { local = blk;       mtdiv8 = 4; }   // Q: MT=32
        else if (blk < 768) { local = blk - 256; mtdiv8 = 8; }   // K: MT=64
        else                { local = blk - 768; mtdiv8 = 8; }   // V: MT=64
        int x = local & 7, y = local >> 3;
        int m = x * mtdiv8 + (y >> 3);
        int n = y & 7;
        bm = m * TBM; bn = n * TBN;
    }
    if (blk < 256)      { X = Xq; W = Wq; bias = bq; outp = Qout;  vmode = 0; }
    else if (blk < 768) { X = Xc; W = Wk; bias = bk; outp = Kout;  vmode = 0; }
    else                { X = Xc; W = Wv; bias = bv; outp = VoutT; vmode = 1; }

    int ar = tid >> 2, ac = (tid & 3) * 8;
    int br = tid >> 2, bc = (tid & 3) * 8;
    const short* ag = X + (size_t)(bm + ar) * D + ac;
    const short* bg = W + (size_t)(bn + br) * D + bc;
    short* aw0 = &Ab[0][ar * TPAD + ac];
    short* aw1 = &Ab[1][ar * TPAD + ac];
    short* bw0 = &Bb[0][br * TPAD + bc];
    short* bw1 = &Bb[1][br * TPAD + bc];

    short8 ra, rb;

#define GLOAD(ks) {                                                            \
        ra = *(const short8*)(ag + (ks) * TBK);                                \
        rb = *(const short8*)(bg + (ks) * TBK); }
#define GDSW0 { *(short8*)aw0 = ra; *(short8*)bw0 = rb; }
#define GDSW1 { *(short8*)aw1 = ra; *(short8*)bw1 = rb; }

    float4v c00 = {0,0,0,0}, c01 = {0,0,0,0}, c02 = {0,0,0,0}, c03 = {0,0,0,0};

#define GCOMP(B)                                                               \
    {                                                                          \
        const short* abase = &Ab[B][(wave * 16 + l15) * TPAD + quad * 8];      \
        const short* bbase = &Bb[B][l15 * TPAD + quad * 8];                    \
        short8 a0 = *(const short8*)(abase);                                   \
        short8 b0 = *(const short8*)(bbase);                                   \
        short8 b1 = *(const short8*)(bbase + 16 * TPAD);                       \
        short8 b2 = *(const short8*)(bbase + 32 * TPAD);                       \
        short8 b3 = *(const short8*)(bbase + 48 * TPAD);                       \
        c00 = __builtin_amdgcn_mfma_f32_16x16x32_bf16(a0, b0, c00, 0, 0, 0);   \
        c01 = __builtin_amdgcn_mfma_f32_16x16x32_bf16(a0, b1, c01, 0, 0, 0);   \
        c02 = __builtin_amdgcn_mfma_f32_16x16x32_bf16(a0, b2, c02, 0, 0, 0);   \
        c03 = __builtin_amdgcn_mfma_f32_16x16x32_bf16(a0, b3, c03, 0, 0, 0);   \
    }

    GLOAD(0);
    GDSW0;
    GLOAD(1);
    __syncthreads();

    for (int t = 0; t < 14; t += 2) {
        GDSW1;
        GLOAD(t + 2);
        GCOMP(0);
        __syncthreads();
        GDSW0;
        GLOAD(t + 3);
        GCOMP(1);
        __syncthreads();
    }
    GDSW1;
    GCOMP(0);
    __syncthreads();
    GCOMP(1);

#undef GLOAD
#undef GDSW0
#undef GDSW1
#undef GCOMP

    float4v accs[4] = {c00, c01, c02, c03};
    if (vmode == 0) {
        int orow = bm + wave * 16 + quad * 4;
#pragma unroll
        for (int nf = 0; nf < 4; nf++) {
            int col = bn + nf * 16 + l15;
            float bb_ = bias[col];
#pragma unroll
            for (int r = 0; r < 4; r++)
                outp[(size_t)(orow + r) * D + col] = f2bf(accs[nf][r] + bb_);
        }
    } else {
        int orow = bm + wave * 16 + quad * 4;   // 4-aligned context base
        int a = (orow & 31) >> 2;
        int posb = (a < 4) ? (8 * a) : (8 * (a - 4) + 4);
        int cp = (orow & ~31) + posb;
#pragma unroll
        for (int nf = 0; nf < 4; nf++) {
            int col = bn + nf * 16 + l15;
            float bb_ = bias[col];
            short4v o;
#pragma unroll
            for (int r = 0; r < 4; r++) o[r] = f2bf(accs[nf][r] + bb_);
            *(short4v*)(outp + (size_t)col * NC + cp) = o;
        }
    }
}

// ---------------------------------------------------------------------------
// TILED output projection: Xf = Att @ Wo^T + bo + resid (f32 out).
// TBM=64 (round-15 PASSED) + XCD remap (MT=32). Grid 256.
// ---------------------------------------------------------------------------
__global__ __launch_bounds__(256) void gemm_out_tiled(
    const short* __restrict__ X, const short* __restrict__ W,
    const float* __restrict__ bias, const float* __restrict__ resid,
    float* __restrict__ out)
{
    __shared__ __align__(16) short Ab[2][TBM * TPAD];   // 10240 B
    __shared__ __align__(16) short Bb[2][TBN * TPAD];   // 10240 B

    int tid = threadIdx.x;
    int wave = tid >> 6, lane = tid & 63;
    int quad = lane >> 4, l15 = lane & 15;

    int blk = blockIdx.x;
    int x = blk & 7, y = blk >> 3;          // y in [0,32)
    int bm = (x * 4 + (y >> 3)) * TBM;      // MT=32
    int bn = (y & 7) * TBN;

    int ar = tid >> 2, ac = (tid & 3) * 8;
    int br = tid >> 2, bc = (tid & 3) * 8;
    const short* ag = X + (size_t)(bm + ar) * D + ac;
    const short* bg = W + (size_t)(bn + br) * D + bc;
    short* aw0 = &Ab[0][ar * TPAD + ac];
    short* aw1 = &Ab[1][ar * TPAD + ac];
    short* bw0 = &Bb[0][br * TPAD + bc];
    short* bw1 = &Bb[1][br * TPAD + bc];

    short8 ra, rb;

#define GLOAD(ks) {                                                            \
        ra = *(const short8*)(ag + (ks) * TBK);                                \
        rb = *(const short8*)(bg + (ks) * TBK); }
#define GDSW0 { *(short8*)aw0 = ra; *(short8*)bw0 = rb; }
#define GDSW1 { *(short8*)aw1 = ra; *(short8*)bw1 = rb; }

    float4v c00 = {0,0,0,0}, c01 = {0,0,0,0}, c02 = {0,0,0,0}, c03 = {0,0,0,0};

#define GCOMP(B)                                                               \
    {                                                                          \
        const short* abase = &Ab[B][(wave * 16 + l15) * TPAD + quad * 8];      \
        const short* bbase = &Bb[B][l15 * TPAD + quad * 8];                    \
        short8 a0 = *(const short8*)(abase);                                   \
        short8 b0 = *(const short8*)(bbase);                                   \
        short8 b1 = *(const short8*)(bbase + 16 * TPAD);                       \
        short8 b2 = *(const short8*)(bbase + 32 * TPAD);                       \
        short8 b3 = *(const short8*)(bbase + 48 * TPAD);                       \
        c00 = __builtin_amdgcn_mfma_f32_16x16x32_bf16(a0, b0, c00, 0, 0, 0);   \
        c01 = __builtin_amdgcn_mfma_f32_16x16x32_bf16(a0, b1, c01, 0, 0, 0);   \
        c02 = __builtin_amdgcn_mfma_f32_16x16x32_bf16(a0, b2, c02, 0, 0, 0);   \
        c03 = __builtin_amdgcn_mfma_f32_16x16x32_bf16(a0, b3, c03, 0, 0, 0);   \
    }

    GLOAD(0);
    GDSW0;
    GLOAD(1);
    __syncthreads();

    for (int t = 0; t < 14; t += 2) {
        GDSW1;
        GLOAD(t + 2);
        GCOMP(0);
        __syncthreads();
        GDSW0;
        GLOAD(t + 3);
        GCOMP(1);
        __syncthreads();
    }
    GDSW1;
    GCOMP(0);
    __syncthreads();
    GCOMP(1);

#undef GLOAD
#undef GDSW0
#undef GDSW1
#undef GCOMP

    float4v accs[4] = {c00, c01, c02, c03};
    int orow = bm + wave * 16 + quad * 4;
#pragma unroll
    for (int nf = 0; nf < 4; nf++) {
        int col = bn + nf * 16 + l15;
        float bb_ = bias[col];
#pragma unroll
        for (int r = 0; r < 4; r++)
            out[(size_t)(orow + r) * D + col] =
                accs[nf][r] + bb_ + resid[(size_t)(orow + r) * D + col];
    }
}

// Fallback: naive res GEMM writing f32 (used with separate layernorm_kernel).
__global__ __launch_bounds__(256) void gemm_bt_bias_res_f32(
    const short* __restrict__ X, const short* __restrict__ W,
    const float* __restrict__ bias, const float* __restrict__ resid,
    float* __restrict__ out, int M)
{
    int wave = threadIdx.x >> 6, lane = threadIdx.x & 63;
    int gt = blockIdx.x * 4 + wave;
    int tm = gt >> 3;
    int tg = gt & 7;
    if (tm >= (M >> 4)) return;
    int l15 = lane & 15, quad = lane >> 4;
    const short* xp = X + (tm * 16 + l15) * D + quad * 8;
    const short* wp = W + (tg * 64 + l15) * D + quad * 8;
    float4v a0 = {0,0,0,0}, a1 = {0,0,0,0}, a2 = {0,0,0,0}, a3 = {0,0,0,0};
#pragma unroll
    for (int k = 0; k < D; k += 32) {
        short8 a  = *(const short8*)(xp + k);
        short8 b0 = *(const short8*)(wp + k);
        short8 b1 = *(const short8*)(wp + 16 * D + k);
        short8 b2 = *(const short8*)(wp + 32 * D + k);
        short8 b3 = *(const short8*)(wp + 48 * D + k);
        a0 = __builtin_amdgcn_mfma_f32_16x16x32_bf16(a, b0, a0, 0, 0, 0);
        a1 = __builtin_amdgcn_mfma_f32_16x16x32_bf16(a, b1, a1, 0, 0, 0);
        a2 = __builtin_amdgcn_mfma_f32_16x16x32_bf16(a, b2, a2, 0, 0, 0);
        a3 = __builtin_amdgcn_mfma_f32_16x16x32_bf16(a, b3, a3, 0, 0, 0);
    }
    int orow = tm * 16 + quad * 4;
    float4v accs[4] = {a0, a1, a2, a3};
#pragma unroll
    for (int j = 0; j < 4; j++) {
        int col = tg * 64 + j * 16 + l15;
        float bv = bias[col];
#pragma unroll
        for (int r = 0; r < 4; r++) {
            int q = orow + r;
            out[q * D + col] = accs[j][r] + bv + resid[q * D + col];
        }
    }
}

// ---------------------------------------------------------------------------
// MFMA flash attention v10 (rounds 12/14/15 PASSED): head-paired v9 body +
// XCD 1D-grid swizzle (FETCH 35 -> 12.4 MB verified). Round-16 established
// that un-pairing (v11) regresses (+4us): the kernel is VALU-issue-bound,
// and pairing's halved dist-VALU beats the occupancy gain. FINAL.
// NOTE: cc-from-global (v7/v8) produced NaN twice — do not reintroduce.
// ---------------------------------------------------------------------------
__global__ __launch_bounds__(256) void attn_mfma_split10(
    const short* __restrict__ Q, const short* __restrict__ K,
    const short* __restrict__ Vp,
    const float* __restrict__ qc, const float* __restrict__ cc,
    const float* __restrict__ log_scale, const float* __restrict__ bph,
    short* __restrict__ Opart, float* __restrict__ Lpart)
{
    __shared__ __align__(16) short Klds[2][32 * KP2];   // 17408 B
    __shared__ __align__(16) short Vlds[2][128 * VP];   // 20480 B
    __shared__ __align__(16) float ccl[512];            //  2048 B (256 ctx)

    int tid = threadIdx.x;
    int wave = tid >> 6, lane = tid & 63;

    // XCD swizzle decode
    int d = blockIdx.x;
    int s = (d & 7) * 128 + (d >> 3);
    int bx = s & 31;
    int by = (s >> 5) & 3;
    int bz = s >> 7;

    int h0 = by * 2;                    // head pair (h0, h0+1)
    int sp = bz;
    int q0 = bx * 64 + wave * 16;
    int quad = lane >> 4, l15 = lane & 15;
    int cbase = sp * CLEN;

    const float LOG2E = 1.4426950408889634f;
    const float escale = 0.125f * LOG2E;
    const float M0L = M0 * LOG2E;
    float ebase = __expf(log_scale[0]);
    float bh0 = ebase * bph[h0] * LOG2E;
    float bh1 = ebase * bph[h0 + 1] * LOG2E;

    const short* qp = Q + (q0 + l15) * D + h0 * HD + quad * 8;
    short8 qa0_0 = *(const short8*)(qp);
    short8 qa1_0 = *(const short8*)(qp + 32);
    short8 qa0_1 = *(const short8*)(qp + 64);
    short8 qa1_1 = *(const short8*)(qp + 96);

    float qx = qc[(q0 + l15) * 2];
    float qy = qc[(q0 + l15) * 2 + 1];

    float lacc0 = 0.f, lacc1 = 0.f;
    float4v O00 = {0,0,0,0}, O01 = {0,0,0,0}, O02 = {0,0,0,0}, O03 = {0,0,0,0};
    float4v O10 = {0,0,0,0}, O11 = {0,0,0,0}, O12 = {0,0,0,0}, O13 = {0,0,0,0};

    int kr_ = tid >> 3, kc_ = tid & 7;
    int vr_ = tid >> 2, vc_ = tid & 3;
    const short* kg  = K + (size_t)h0 * HD + kc_ * 8;            // +(c0+kr_)*D
    const short* vg0 = Vp + (size_t)(h0 * HD + vr_) * NC + vc_ * 8;       // +c0
    const short* vg1 = Vp + (size_t)(h0 * HD + 64 + vr_) * NC + vc_ * 8;  // +c0
    short* kw0a = &Klds[0][kr_ * KP2 + kc_ * 8];
    short* kw1a = &Klds[1][kr_ * KP2 + kc_ * 8];
    short* vw0a = &Vlds[0][vr_ * VP + vc_ * 8];
    short* vw0b = &Vlds[0][(64 + vr_) * VP + vc_ * 8];
    short* vw1a = &Vlds[1][vr_ * VP + vc_ * 8];
    short* vw1b = &Vlds[1][(64 + vr_) * VP + vc_ * 8];

    short8 rka, rkb, rva, rvb;   // staged regs for the next tile

#define LOADR(c0_)                                                             \
    {                                                                          \
        const short* kp_ = kg + (size_t)((c0_) + kr_) * D;                     \
        rka = *(const short8*)(kp_);                                           \
        rkb = *(const short8*)(kp_ + 64);                                      \
        rva = *(const short8*)(vg0 + (c0_));                                   \
        rvb = *(const short8*)(vg1 + (c0_));                                   \
    }

#define DSW0 { *(short8*)kw0a = rka; *(short8*)(kw0a + 64) = rkb;              \
               *(short8*)vw0a = rva; *(short8*)vw0b = rvb; }
#define DSW1 { *(short8*)kw1a = rka; *(short8*)(kw1a + 64) = rkb;              \
               *(short8*)vw1a = rva; *(short8*)vw1b = rvb; }

    const float2* ccp = (const float2*)ccl;

#define HEAD(hoff, QA0, QA1, BH, LACC, OA, OB, OC, OD)                         \
    {                                                                          \
        short8 k00 = *(const short8*)(kb + l15 * KP2 + (hoff) + quad * 8);     \
        short8 k01 = *(const short8*)(kb + l15 * KP2 + (hoff) + 32 + quad * 8);\
        short8 k10 = *(const short8*)(kb + (16 + l15) * KP2 + (hoff) + quad * 8);\
        short8 k11 = *(const short8*)(kb + (16 + l15) * KP2 + (hoff) + 32 + quad * 8);\
        float4v s0 = {0,0,0,0}, s1 = {0,0,0,0};                                \
        s0 = __builtin_amdgcn_mfma_f32_16x16x32_bf16(k00, QA0, s0, 0, 0, 0);   \
        s0 = __builtin_amdgcn_mfma_f32_16x16x32_bf16(k01, QA1, s0, 0, 0, 0);   \
        s1 = __builtin_amdgcn_mfma_f32_16x16x32_bf16(k10, QA0, s1, 0, 0, 0);   \
        s1 = __builtin_amdgcn_mfma_f32_16x16x32_bf16(k11, QA1, s1, 0, 0, 0);   \
        short8 v0 = *(const short8*)(vb + ((hoff) / 64 * 64 + l15) * VP + quad * 8);       \
        short8 v1 = *(const short8*)(vb + ((hoff) / 64 * 64 + 16 + l15) * VP + quad * 8);  \
        short8 v2 = *(const short8*)(vb + ((hoff) / 64 * 64 + 32 + l15) * VP + quad * 8);  \
        short8 v3 = *(const short8*)(vb + ((hoff) / 64 * 64 + 48 + l15) * VP + quad * 8);  \
        float p00 = exp2f(__fmaf_rn(s0[0], escale, __fmaf_rn(-(BH), dA0, -M0L)));\
        float p01 = exp2f(__fmaf_rn(s0[1], escale, __fmaf_rn(-(BH), dA1, -M0L)));\
        float p02 = exp2f(__fmaf_rn(s0[2], escale, __fmaf_rn(-(BH), dA2, -M0L)));\
        float p03 = exp2f(__fmaf_rn(s0[3], escale, __fmaf_rn(-(BH), dA3, -M0L)));\
        float p10 = exp2f(__fmaf_rn(s1[0], escale, __fmaf_rn(-(BH), dB0, -M0L)));\
        float p11 = exp2f(__fmaf_rn(s1[1], escale, __fmaf_rn(-(BH), dB1, -M0L)));\
        float p12 = exp2f(__fmaf_rn(s1[2], escale, __fmaf_rn(-(BH), dB2, -M0L)));\
        float p13 = exp2f(__fmaf_rn(s1[3], escale, __fmaf_rn(-(BH), dB3, -M0L)));\
        LACC += ((p00 + p01) + (p02 + p03)) + ((p10 + p11) + (p12 + p13));     \
        int4v pw;                                                              \
        pw.x = cvtpk(p00, p01); pw.y = cvtpk(p02, p03);                        \
        pw.z = cvtpk(p10, p11); pw.w = cvtpk(p12, p13);                        \
        short8 pa = __builtin_bit_cast(short8, pw);                            \
        OA = __builtin_amdgcn_mfma_f32_16x16x32_bf16(pa, v0, OA, 0, 0, 0);     \
        OB = __builtin_amdgcn_mfma_f32_16x16x32_bf16(pa, v1, OB, 0, 0, 0);     \
        OC = __builtin_amdgcn_mfma_f32_16x16x32_bf16(pa, v2, OC, 0, 0, 0);     \
        OD = __builtin_amdgcn_mfma_f32_16x16x32_bf16(pa, v3, OD, 0, 0, 0);     \
    }

#define COMPUTE_TILE(B, lo)                                                    \
    {                                                                          \
        const short* kb = &Klds[B][0];                                         \
        const short* vb = &Vlds[B][0];                                         \
        float2 ca0 = ccp[(lo) + 4 * quad + 0], cb0 = ccp[(lo) + 16 + 4 * quad + 0];\
        float2 ca1 = ccp[(lo) + 4 * quad + 1], cb1 = ccp[(lo) + 16 + 4 * quad + 1];\
        float2 ca2 = ccp[(lo) + 4 * quad + 2], cb2 = ccp[(lo) + 16 + 4 * quad + 2];\
        float2 ca3 = ccp[(lo) + 4 * quad + 3], cb3 = ccp[(lo) + 16 + 4 * quad + 3];\
        float dx, dy;                                                          \
        dx = qx - ca0.x; dy = qy - ca0.y;                                      \
        float dA0 = __builtin_amdgcn_sqrtf(__fmaf_rn(dx, dx, dy * dy));        \
        dx = qx - ca1.x; dy = qy - ca1.y;                                      \
        float dA1 = __builtin_amdgcn_sqrtf(__fmaf_rn(dx, dx, dy * dy));        \
        dx = qx - ca2.x; dy = qy - ca2.y;                                      \
        float dA2 = __builtin_amdgcn_sqrtf(__fmaf_rn(dx, dx, dy * dy));        \
        dx = qx - ca3.x; dy = qy - ca3.y;                                      \
        float dA3 = __builtin_amdgcn_sqrtf(__fmaf_rn(dx, dx, dy * dy));        \
        dx = qx - cb0.x; dy = qy - cb0.y;                                      \
        float dB0 = __builtin_amdgcn_sqrtf(__fmaf_rn(dx, dx, dy * dy));        \
        dx = qx - cb1.x; dy = qy - cb1.y;                                      \
        float dB1 = __builtin_amdgcn_sqrtf(__fmaf_rn(dx, dx, dy * dy));        \
        dx = qx - cb2.x; dy = qy - cb2.y;                                      \
        float dB2 = __builtin_amdgcn_sqrtf(__fmaf_rn(dx, dx, dy * dy));        \
        dx = qx - cb3.x; dy = qy - cb3.y;                                      \
        float dB3 = __builtin_amdgcn_sqrtf(__fmaf_rn(dx, dx, dy * dy));        \
        HEAD(0,  qa0_0, qa1_0, bh0, lacc0, O00, O01, O02, O03)                 \
        HEAD(64, qa0_1, qa1_1, bh1, lacc1, O10, O11, O12, O13)                 \
    }

    // ---- prologue: cc phase A (256 ctx) -> LDS, tile0 -> buf0, tile1 -> regs
    ((float2*)ccl)[tid] = ((const float2*)cc)[cbase + tid];
    LOADR(cbase);
    DSW0;
    LOADR(cbase + 32);
    __syncthreads();

    // ---- main loop: 16 tiles, 2x-unrolled (static buffer indices) ----
    for (int t = 0; t < NT - 2; t += 2) {
        int c0 = cbase + t * 32;
        if (t == 8) {
            ((float2*)ccl)[tid] = ((const float2*)cc)[cbase + 256 + tid];
            __syncthreads();
        }
        DSW1;
        LOADR(c0 + 64);
        COMPUTE_TILE(0, (t & 7) * 32);
        __syncthreads();
        DSW0;
        LOADR(c0 + 96);
        COMPUTE_TILE(1, (t & 7) * 32 + 32);
        __syncthreads();
    }
    DSW1;
    COMPUTE_TILE(0, 192);   // tile 14, rel (14-8)*32
    __syncthreads();
    COMPUTE_TILE(1, 224);   // tile 15, rel (15-8)*32

#undef LOADR
#undef DSW0
#undef DSW1
#undef HEAD
#undef COMPUTE_TILE

    lacc0 += __shfl_xor(lacc0, 16);
    lacc0 += __shfl_xor(lacc0, 32);
    lacc1 += __shfl_xor(lacc1, 16);
    lacc1 += __shfl_xor(lacc1, 32);

    long base0 = (long)(sp * H + h0) * NQ;
    long base1 = base0 + NQ;
    float4v Oarr0[4] = {O00, O01, O02, O03};
    float4v Oarr1[4] = {O10, O11, O12, O13};
#pragma unroll
    for (int t = 0; t < 4; t++) {
#pragma unroll
        for (int r = 0; r < 4; r++) {
            int q = q0 + quad * 4 + r;
            Opart[(base0 + q) * HD + t * 16 + l15] = f2bf(Oarr0[t][r]);
            Opart[(base1 + q) * HD + t * 16 + l15] = f2bf(Oarr1[t][r]);
        }
    }
    if (lane < 16) {
        Lpart[base0 + q0 + lane] = lacc0;
        Lpart[base1 + q0 + lane] = lacc1;
    }
}

// Plain-sum combine (all splits share fixed max M0) -> bf16 Att.
__global__ __launch_bounds__(256) void attn_combine(
    const short* __restrict__ Opart, const float* __restrict__ Lpart,
    short* __restrict__ Att)
{
    int id = blockIdx.x * 256 + threadIdx.x;   // over H*NQ*HD = 2^20
    int d = id & 63;
    int q = (id >> 6) & (NQ - 1);
    int h = id >> 17;
    float L = 0.f, acc = 0.f;
#pragma unroll
    for (int s = 0; s < SPLIT; s++) {
        long b = (long)(s * H + h) * NQ + q;
        L   += Lpart[b];
        acc += bf2f(Opart[b * HD + d]);
    }
    Att[q * D + h * HD + d] = f2bf(acc / L);
}

// ---------------------------------------------------------------------------
// Fallback single-pass attention (exact online softmax) if ws is too small.
// Expects V row-major [NC][D], unscaled Q.
// ---------------------------------------------------------------------------
__global__ __launch_bounds__(256) void attn_mfma(
    const short* __restrict__ Q, const short* __restrict__ K,
    const short* __restrict__ V,
    const float* __restrict__ qc, const float* __restrict__ cc,
    const float* __restrict__ log_scale, const float* __restrict__ bph,
    short* __restrict__ out)
{
    __shared__ short Vt[HD][48];
    __shared__ short P[4][16][48];
    int wave = threadIdx.x >> 6, lane = threadIdx.x & 63;
    int h = blockIdx.y;
    int q0 = blockIdx.x * 64 + wave * 16;
    int quad = lane >> 4, l15 = lane & 15;
    const float scale = 0.125f;
    float bh = __expf(log_scale[0]) * bph[h];
    const short* qp = Q + (q0 + l15) * D + h * HD + quad * 8;
    short8 qa0 = *(const short8*)(qp);
    short8 qa1 = *(const short8*)(qp + 32);
    float qx[4], qy[4];
#pragma unroll
    for (int r = 0; r < 4; r++) {
        int q = q0 + quad * 4 + r;
        qx[r] = qc[q * 2]; qy[r] = qc[q * 2 + 1];
    }
    float m[4], l[4];
    float4v O[4];
#pragma unroll
    for (int r = 0; r < 4; r++) { m[r] = -1e30f; l[r] = 0.f; }
#pragma unroll
    for (int t = 0; t < 4; t++) O[t] = (float4v){0.f, 0.f, 0.f, 0.f};
    for (int c0 = 0; c0 < NC; c0 += 32) {
        __syncthreads();
        {
            int c = threadIdx.x >> 3;
            int dblk = (threadIdx.x & 7) * 8;
            short8 vv = *(const short8*)(V + (c0 + c) * D + h * HD + dblk);
#pragma unroll
            for (int j = 0; j < 8; j++) Vt[dblk + j][c] = vv[j];
        }
        const short* kp0 = K + (c0 + l15) * D + h * HD + quad * 8;
        const short* kp1 = kp0 + 16 * D;
        short8 kb00 = *(const short8*)(kp0);
        short8 kb01 = *(const short8*)(kp0 + 32);
        short8 kb10 = *(const short8*)(kp1);
        short8 kb11 = *(const short8*)(kp1 + 32);
        float4v s0 = {0,0,0,0}, s1 = {0,0,0,0};
        s0 = __builtin_amdgcn_mfma_f32_16x16x32_bf16(qa0, kb00, s0, 0, 0, 0);
        s0 = __builtin_amdgcn_mfma_f32_16x16x32_bf16(qa1, kb01, s0, 0, 0, 0);
        s1 = __builtin_amdgcn_mfma_f32_16x16x32_bf16(qa0, kb10, s1, 0, 0, 0);
        s1 = __builtin_amdgcn_mfma_f32_16x16x32_bf16(qa1, kb11, s1, 0, 0, 0);
        int cA = c0 + l15, cB = cA + 16;
        float cxA = cc[cA * 2], cyA = cc[cA * 2 + 1];
        float cxB = cc[cB * 2], cyB = cc[cB * 2 + 1];
#pragma unroll
        for (int r = 0; r < 4; r++) {
            float dxA = qx[r] - cxA, dyA = qy[r] - cyA;
            float dxB = qx[r] - cxB, dyB = qy[r] - cyB;
            float v0 = s0[r] * scale - bh * sqrtf(dxA * dxA + dyA * dyA);
            float v1 = s1[r] * scale - bh * sqrtf(dxB * dxB + dyB * dyB);
            float mx = fmaxf(v0, v1);
#pragma unroll
            for (int off = 1; off < 16; off <<= 1) mx = fmaxf(mx, __shfl_xor(mx, off));
            float mnew = fmaxf(m[r], mx);
            float alpha = __expf(m[r] - mnew);
            float p0 = __expf(v0 - mnew);
            float p1 = __expf(v1 - mnew);
            float ps = p0 + p1;
#pragma unroll
            for (int off = 1; off < 16; off <<= 1) ps += __shfl_xor(ps, off);
            l[r] = l[r] * alpha + ps;
            m[r] = mnew;
#pragma unroll
            for (int t = 0; t < 4; t++) O[t][r] *= alpha;
            P[wave][quad * 4 + r][l15]      = f2bf(p0);
            P[wave][quad * 4 + r][16 + l15] = f2bf(p1);
        }
        __syncthreads();
        short8 pa = *(const short8*)(&P[wave][l15][quad * 8]);
#pragma unroll
        for (int t = 0; t < 4; t++) {
            short8 vb = *(const short8*)(&Vt[t * 16 + l15][quad * 8]);
            O[t] = __builtin_amdgcn_mfma_f32_16x16x32_bf16(pa, vb, O[t], 0, 0, 0);
        }
    }
#pragma unroll
    for (int t = 0; t < 4; t++) {
#pragma unroll
        for (int r = 0; r < 4; r++) {
            int q = q0 + quad * 4 + r;
            out[q * D + h * HD + t * 16 + l15] = f2bf(O[t][r] / l[r]);
        }
    }
}

// ---------------------------------------------------------------------------
// Row LayerNorm: one wave per row of 512 f32, output f32. Grid NQ/4 = 512.
// ---------------------------------------------------------------------------
__global__ __launch_bounds__(256) void layernorm_kernel(
    const float* __restrict__ X, const float* __restrict__ g,
    const float* __restrict__ b, float* __restrict__ out)
{
    int wave = threadIdx.x >> 6, lane = threadIdx.x & 63;
    int row = blockIdx.x * 4 + wave;
    const float* xp = X + row * D;
    float v[8];
    float s = 0.f;
#pragma unroll
    for (int i = 0; i < 8; i++) { v[i] = xp[lane + i * 64]; s += v[i]; }
#pragma unroll
    for (int off = 1; off < 64; off <<= 1) s += __shfl_xor(s, off);
    float mu = s * (1.f / D);
    float var = 0.f;
#pragma unroll
    for (int i = 0; i < 8; i++) { float d = v[i] - mu; var += d * d; }
#pragma unroll
    for (int off = 1; off < 64; off <<= 1) var += __shfl_xor(var, off);
    float rstd = rsqrtf(var * (1.f / D) + 1e-5f);
#pragma unroll
    for (int i = 0; i < 8; i++) {
        int c = lane + i * 64;
        out[row * D + c] = (v[i] - mu) * rstd * g[c] + b[c];
    }
}

extern "C" void kernel_launch(void* const* d_in, const int* in_sizes, int n_in,
                              void* d_out, int out_size, void* d_ws, size_t ws_size,
                              hipStream_t stream) {
    const float* query_repr     = (const float*)d_in[0];
    const float* context_repr   = (const float*)d_in[1];
    const float* query_coords   = (const float*)d_in[2];
    const float* context_coords = (const float*)d_in[3];
    const float* Wq = (const float*)d_in[4];
    const float* bq = (const float*)d_in[5];
    const float* Wk = (const float*)d_in[6];
    const float* bk = (const float*)d_in[7];
    const float* Wv = (const float*)d_in[8];
    const float* bv = (const float*)d_in[9];
    const float* Wo = (const float*)d_in[10];
    const float* bo = (const float*)d_in[11];
    const float* ln_g = (const float*)d_in[12];
    const float* ln_b = (const float*)d_in[13];
    const float* log_scale = (const float*)d_in[14];
    const float* bph = (const float*)d_in[15];

    short* ws = (short*)d_ws;
    short* Xq_bf = ws;                       // 1,048,576 shorts
    short* Xc_bf = Xq_bf + NQ * D;           // 2,097,152
    short* Wq_bf = Xc_bf + NC * D;           //   262,144 x4
    short* Wk_bf = Wq_bf + D * D;
    short* Wv_bf = Wk_bf + D * D;
    short* Wo_bf = Wv_bf + D * D;
    short* Qw  = Wo_bf + D * D;              // 1,048,576
    short* Kw  = Qw + NQ * D;                // 2,097,152
    short* Vw  = Kw + NC * D;                // 2,097,152 (Vp [D][NC] permuted)
    short* Att = Vw + NC * D;                // 1,048,576
    float* Xf  = (float*)(Att + NQ * D);     // 1,048,576 f32
    short* Opart = (short*)(Xf + NQ * D);    // SPLIT*H*NQ*HD bf16 = 16.8 MB
    float* Lpart = (float*)(Opart + (size_t)SPLIT * H * NQ * HD);  // 0.5 MB
    size_t ws_needed_split = ((char*)(Lpart + (size_t)SPLIT * H * NQ)) - (char*)d_ws;

    // 1. cast MFMA operands to bf16
    cast_all<<<dim3(4096), 256, 0, stream>>>(
        query_repr, context_repr, Wq, Wk, Wv, Wo, Xq_bf);

    if (ws_size >= ws_needed_split) {
        // 2. TILED Q+K+V projection (TBM=64, grid 1280 = 5 blocks/CU)
        gemm_qkv_tiled<<<dim3(1280), 256, 0, stream>>>(
            Xq_bf, Xc_bf, Wq_bf, Wk_bf, Wv_bf, bq, bk, bv, Qw, Kw, Vw);
        // 3. attention (v10: XCD-swizzled grid) + combine
        attn_mfma_split10<<<dim3(1024), 256, 0, stream>>>(
            Qw, Kw, Vw, query_coords, context_coords, log_scale, bph,
            Opart, Lpart);
        attn_combine<<<dim3(H * NQ * HD / 256), 256, 0, stream>>>(
            Opart, Lpart, Att);
        // 4. TILED output projection + residual (TBM=64, grid 256) -> Xf
        gemm_out_tiled<<<dim3(256), 256, 0, stream>>>(
            Att, Wo_bf, bo, query_repr, Xf);
        // 5. LayerNorm -> f32 output
        layernorm_kernel<<<dim3(NQ / 4), 256, 0, stream>>>(
            Xf, ln_g, ln_b, (float*)d_out);
    } else {
        gemm_bt_bias<<<dim3((NQ / 16) * 8 / 4), 256, 0, stream>>>(
            Xq_bf, Wq_bf, bq, Qw, NQ);
        gemm_bt_bias<<<dim3((NC / 16) * 8 / 4), 256, 0, stream>>>(
            Xc_bf, Wk_bf, bk, Kw, NC);
        gemm_bt_bias<<<dim3((NC / 16) * 8 / 4), 256, 0, stream>>>(
            Xc_bf, Wv_bf, bv, Vw, NC);
        attn_mfma<<<dim3(NQ / 64, H), 256, 0, stream>>>(
            Qw, Kw, Vw, query_coords, context_coords, log_scale, bph, Att);
        gemm_bt_bias_res_f32<<<dim3((NQ / 16) * 8 / 4), 256, 0, stream>>>(
            Att, Wo_bf, bo, query_repr, Xf, NQ);
        layernorm_kernel<<<dim3(NQ / 4), 256, 0, stream>>>(
            Xf, ln_g, ln_b, (float*)d_out);
    }
}